// Round 7
// baseline (229.456 us; speedup 1.0000x reference)
//
#include <hip/hip_runtime.h>
#include <stdint.h>
#include <stddef.h>

// Problem constants
#define HB 8
#define HN 1024
#define HC 768
#define HH 12
#define HD 64
#define ROWS (HB*HN)      // 8192
#define BH (HB*HH)        // 96

using s16x4  = __attribute__((ext_vector_type(4))) short;
using bf16x8 = __attribute__((ext_vector_type(8))) short;
using f32x4  = __attribute__((ext_vector_type(4))) float;

__device__ __forceinline__ short f2bf(float f) {
  union { float f; uint32_t u; } c; c.f = f;
  uint32_t u = c.u;
  uint32_t r = (u + 0x7fffu + ((u >> 16) & 1u)) >> 16;   // RNE
  return (short)r;
}
__device__ __forceinline__ float bf2f(short s) {
  union { uint32_t u; float f; } c; c.u = ((uint32_t)(uint16_t)s) << 16;
  return c.f;
}
// pack two f32 -> {bf16(a) | bf16(b)<<16} with RNE, via v_perm_b32
__device__ __forceinline__ uint32_t pack_bf16_rne(float a, float b) {
  union { float f; uint32_t u; } ca, cb; ca.f = a; cb.f = b;
  uint32_t ra = ca.u + 0x7fffu + ((ca.u >> 16) & 1u);
  uint32_t rb = cb.u + 0x7fffu + ((cb.u >> 16) & 1u);
  return __builtin_amdgcn_perm(rb, ra, 0x07060302);  // {rb[31:16], ra[31:16]}
}
__device__ __forceinline__ float fast_exp2(float x) {
#if __has_builtin(__builtin_amdgcn_exp2f)
  return __builtin_amdgcn_exp2f(x);
#else
  return exp2f(x);
#endif
}
__device__ __forceinline__ f32x4 mfma16(bf16x8 a, bf16x8 b, f32x4 c) {
  return __builtin_amdgcn_mfma_f32_16x16x32_bf16(a, b, c, 0, 0, 0);
}
// async global->LDS, 16B per lane. LDS dest MUST be wave-uniform base + lane*16.
__device__ __forceinline__ void gll16(const void* g, void* l) {
  __builtin_amdgcn_global_load_lds((const __attribute__((address_space(1))) void*)g,
                                   (__attribute__((address_space(3))) void*)l,
                                   16, 0, 0);
}

// ---------------- fused f32 -> bf16 convert for all 3 inputs ----------------
__global__ void cvt3_kernel(const float* __restrict__ x,  short* __restrict__ xb,  int n0,
                            const float* __restrict__ wq, short* __restrict__ wqb, int n1,
                            const float* __restrict__ wp, short* __restrict__ wpb, int n2) {
  int i = blockIdx.x * 256 + threadIdx.x;        // index in float4 units
  const float* in; short* out;
  if (i < n0)            { in = x;  out = xb;  }
  else if (i < n0 + n1)  { i -= n0; in = wq; out = wqb; }
  else if (i < n0 + n1 + n2) { i -= n0 + n1; in = wp; out = wpb; }
  else return;
  float4 v = ((const float4*)in)[i];
  s16x4 o;
  o.x = f2bf(v.x); o.y = f2bf(v.y); o.z = f2bf(v.z); o.w = f2bf(v.w);
  ((s16x4*)out)[i] = o;
}

__device__ __forceinline__ void store_c(float* p, float v) { *p = v; }
__device__ __forceinline__ void store_c(short* p, float v) { *p = f2bf(v); }

// ---------------- GEMM 1: qkv = x*Wqkv^T, fused LN(q,k) + fused V-transpose --
// R7: 1D grid + XCD-aware decode (xcd=bid&7 gets y-slice [8*xcd,8*xcd+8) x all
// 18 x-tiles: per-XCD L2 set = A-slice 1.6 MB + B 3.5 MB ~ 4 MB L2).
// v-blocks (bx>=12) transpose their 128x128 tile through the dead As/Bs LDS
// and write Vtb directly (key-permuted per 64-group) -> vtrans kernel gone.
__global__ __launch_bounds__(256) void gemm_qkv(const short* __restrict__ A,
                                                const short* __restrict__ Bw,
                                                short* __restrict__ Qb,
                                                short* __restrict__ Kb,
                                                short* __restrict__ Vtb) {
  const int K = HC;
  __shared__ short sm[2*128*64];
  short* As = sm;
  short* Bs = sm + 128*64;
  const int bid = blockIdx.x;
  const int xcd = bid & 7, lin = bid >> 3;      // 144 blocks per XCD
  const int bx = lin % 18, by = xcd*8 + lin/18; // x fast within XCD
  const int m0 = by * 128, n0 = bx * 128;
  const int tid = threadIdx.x;
  const int lane = tid & 63, w = tid >> 6, quad = lane >> 4, lc = lane & 15;
  const int wr = w >> 1, wc = w & 1;
  f32x4 acc[4][4] = {};
  for (int kt = 0; kt < K; kt += 64) {
#pragma unroll
    for (int i = 0; i < 4; ++i) {
      const int chunk = i*256 + tid;
      const int r = chunk >> 3, cb = chunk & 7;
      const int cbs = cb ^ (r & 7);
      gll16(A  + (size_t)(m0 + r)*K + kt + cbs*8, (void*)(As + (size_t)chunk*8));
      gll16(Bw + (size_t)(n0 + r)*K + kt + cbs*8, (void*)(Bs + (size_t)chunk*8));
    }
    __syncthreads();
#pragma unroll
    for (int kk = 0; kk < 2; ++kk) {
      bf16x8 af[4], bfr[4];
      const int kb = kk*4 + quad;
#pragma unroll
      for (int mt = 0; mt < 4; ++mt)
        af[mt] = *(const bf16x8*)(As + (wr*64 + mt*16 + lc)*64 + (kb ^ (lc & 7))*8);
#pragma unroll
      for (int nt = 0; nt < 4; ++nt)
        bfr[nt] = *(const bf16x8*)(Bs + (wc*64 + nt*16 + lc)*64 + (kb ^ (lc & 7))*8);
#pragma unroll
      for (int mt = 0; mt < 4; ++mt)
#pragma unroll
        for (int nt = 0; nt < 4; ++nt)
          acc[mt][nt] = mfma16(af[mt], bfr[nt], acc[mt][nt]);
    }
    __syncthreads();
  }
  // epilogue (C/D: col=nt*16+lc, row=quad*4+r)
  const int b = m0 >> 10;
  if (bx < 12) {
    const int cg = n0 + wc*64;
    const int t = cg / HC;                // 0=q, 1=k
    const int h = (cg % HC) / HD;
    const int bh = b*HH + h;
    short* outp = (t == 0) ? Qb : Kb;
    const float sc = (t == 0) ? 0.125f : 1.0f;   // SCALE = 64^-0.5 for q
#pragma unroll
    for (int mt = 0; mt < 4; ++mt)
#pragma unroll
      for (int r = 0; r < 4; ++r) {
        float s1 = (acc[mt][0][r] + acc[mt][1][r]) + (acc[mt][2][r] + acc[mt][3][r]);
        float s2 = acc[mt][0][r]*acc[mt][0][r];
        s2 = __builtin_fmaf(acc[mt][1][r], acc[mt][1][r], s2);
        s2 = __builtin_fmaf(acc[mt][2][r], acc[mt][2][r], s2);
        s2 = __builtin_fmaf(acc[mt][3][r], acc[mt][3][r], s2);
#pragma unroll
        for (int off = 1; off < 16; off <<= 1) {
          s1 += __shfl_xor(s1, off);
          s2 += __shfl_xor(s2, off);
        }
        const float mean = s1 * (1.0f/64.0f);
        const float var  = s2 * (1.0f/64.0f) - mean*mean;
        const float inv  = rsqrtf(var + 1e-5f) * sc;
        const int n_in = (m0 & 1023) + wr*64 + mt*16 + quad*4 + r;
        short* rowp = outp + ((size_t)bh*HN + n_in)*HD;
#pragma unroll
        for (int nt = 0; nt < 4; ++nt)
          rowp[nt*16 + lc] = f2bf((acc[mt][nt][r] - mean) * inv);
      }
  } else {
    // v: transpose via LDS overlay (As/Bs dead) in two 64-row passes,
    // write Vtb [bh][d][n] with 64-group key-permute c=(k&15)*4+(k>>4)
    short (*Tt)[132] = (short(*)[132])sm;   // 64 x 132 shorts = 16.9 KB
    const int h0 = (bx - 12) * 2;
    const int nb = m0 & 1023;               // n base within batch
#pragma unroll
    for (int p = 0; p < 2; ++p) {
      if (wr == p) {
#pragma unroll
        for (int mt = 0; mt < 4; ++mt)
#pragma unroll
          for (int nt = 0; nt < 4; ++nt)
#pragma unroll
            for (int r = 0; r < 4; ++r)
              Tt[mt*16 + quad*4 + r][wc*64 + nt*16 + lc] = f2bf(acc[mt][nt][r]);
      }
      __syncthreads();
#pragma unroll
      for (int it = 0; it < 4; ++it) {
        const int id = it*256 + tid;
        const int dd = id >> 3, j = id & 7;     // dd in [0,128), j in [0,8)
        bf16x8 o;
#pragma unroll
        for (int u = 0; u < 8; ++u) {
          const int c = j*8 + u;                // storage col within 64-group
          const int k = (c & 3)*16 + (c >> 2);  // key row in Tt
          o[u] = Tt[k][dd];
        }
        const int bhv = b*HH + h0 + (dd >> 6);
        *(bf16x8*)(Vtb + ((size_t)bhv*HD + (dd & 63))*HN + nb + p*64 + j*8) = o;
      }
      __syncthreads();
    }
  }
}

// ---------------- GEMM 2: out = AO * Wproj^T (f32 out), XCD-remapped --------
__global__ __launch_bounds__(256) void gemm_bt_f32(const short* __restrict__ A,
                                                   const short* __restrict__ Bw,
                                                   float* __restrict__ C,
                                                   int M, int N, int K) {
  __shared__ short As[128*64];
  __shared__ short Bs[128*64];
  const int bid = blockIdx.x;
  const int xcd = bid & 7, lin = bid >> 3;      // 48 blocks per XCD
  const int bx = lin % 6, by = xcd*8 + lin/6;
  const int m0 = by * 128, n0 = bx * 128;
  const int tid = threadIdx.x;
  const int lane = tid & 63, w = tid >> 6, quad = lane >> 4, lc = lane & 15;
  const int wr = w >> 1, wc = w & 1;
  f32x4 acc[4][4] = {};
  for (int kt = 0; kt < K; kt += 64) {
#pragma unroll
    for (int i = 0; i < 4; ++i) {
      const int chunk = i*256 + tid;
      const int r = chunk >> 3, cb = chunk & 7;
      const int cbs = cb ^ (r & 7);
      gll16(A  + (size_t)(m0 + r)*K + kt + cbs*8, (void*)(As + (size_t)chunk*8));
      gll16(Bw + (size_t)(n0 + r)*K + kt + cbs*8, (void*)(Bs + (size_t)chunk*8));
    }
    __syncthreads();
#pragma unroll
    for (int kk = 0; kk < 2; ++kk) {
      bf16x8 af[4], bfr[4];
      const int kb = kk*4 + quad;
#pragma unroll
      for (int mt = 0; mt < 4; ++mt)
        af[mt] = *(const bf16x8*)(As + (wr*64 + mt*16 + lc)*64 + (kb ^ (lc & 7))*8);
#pragma unroll
      for (int nt = 0; nt < 4; ++nt)
        bfr[nt] = *(const bf16x8*)(Bs + (wc*64 + nt*16 + lc)*64 + (kb ^ (lc & 7))*8);
#pragma unroll
      for (int mt = 0; mt < 4; ++mt)
#pragma unroll
        for (int nt = 0; nt < 4; ++nt)
          acc[mt][nt] = mfma16(af[mt], bfr[nt], acc[mt][nt]);
    }
    __syncthreads();
  }
#pragma unroll
  for (int mt = 0; mt < 4; ++mt)
#pragma unroll
    for (int nt = 0; nt < 4; ++nt)
#pragma unroll
      for (int r = 0; r < 4; ++r) {
        const int row = m0 + wr*64 + mt*16 + quad*4 + r;
        const int col = n0 + wc*64 + nt*16 + lc;
        store_c(C + (size_t)row*N + col, acc[mt][nt][r]);
      }
}

// ---------------- flash attention (64-key chunks, XCD-remapped) --------------
// R6 structure (proven: no spills, 4 blocks/CU) + R7 XCD decode: each XCD owns
// 12 bh -> its K/V/Q working set stays in its private L2.
__global__ __launch_bounds__(256, 4) void attn_kernel(const short* __restrict__ Qb,
                                                      const short* __restrict__ Kb,
                                                      const short* __restrict__ Vtb,
                                                      short* __restrict__ AOb) {
  const int blk = blockIdx.x;
  const int xcd = blk & 7, lin = blk >> 3;      // 192 blocks per XCD
  const int bh = xcd*12 + lin % 12, qt = lin / 12;
  const int b = bh / HH, h = bh % HH;
  const int tid = threadIdx.x, w = tid >> 6, lane = tid & 63;
  const int quad = lane >> 4, lc = lane & 15;

  __shared__ short Ks [64][72];      // K chunk: row=key(natural), padded
  __shared__ short Vts[64][72];      // V chunk: row=d, cols=64 keys permuted
  __shared__ short Ps [4][16][72];   // per-wave P stash, permuted key space

  // Q A-fragments: A[m=lane&15][k=quad*8+j]
  const int mrow = qt*64 + w*16 + lc;
  bf16x8 aq[2];
  aq[0] = *(const bf16x8*)(Qb + ((size_t)bh*HN + mrow)*HD + quad*8);
  aq[1] = *(const bf16x8*)(Qb + ((size_t)bh*HN + mrow)*HD + 32 + quad*8);

  const short* kbh = Kb  + (size_t)bh*HN*HD;
  const short* vbh = Vtb + (size_t)bh*HD*HN;

  f32x4 oacc[4] = {};
  float l_i[4] = {0.f, 0.f, 0.f, 0.f};

  // staging regs: c = i*256+tid in [0,512); row=c>>3 in [0,64), cb=c&7
  bf16x8 gk[2], gv[2];
#pragma unroll
  for (int i = 0; i < 2; ++i) {
    const int c = i*256 + tid;
    gk[i] = *(const bf16x8*)(kbh + (size_t)(c >> 3)*HD + (c & 7)*8);
    gv[i] = *(const bf16x8*)(vbh + (size_t)(c >> 3)*HN + (c & 7)*8);
  }
#pragma unroll
  for (int i = 0; i < 2; ++i) {
    const int c = i*256 + tid;
    *(bf16x8*)(&Ks [c >> 3][(c & 7)*8]) = gk[i];
    *(bf16x8*)(&Vts[c >> 3][(c & 7)*8]) = gv[i];
  }
  __syncthreads();

  const float LOG2E = 1.44269504f;
  const float MB2   = 8.0f * 1.44269504f;   // fixed max * log2(e)

  for (int ck = 0; ck < 16; ++ck) {
    // prefetch chunk ck+1 into registers (overlaps with compute below)
    if (ck < 15) {
      const int nn0 = (ck + 1)*64;
#pragma unroll
      for (int i = 0; i < 2; ++i) {
        const int c = i*256 + tid;
        gk[i] = *(const bf16x8*)(kbh + (size_t)(nn0 + (c >> 3))*HD + (c & 7)*8);
        gv[i] = *(const bf16x8*)(vbh + (size_t)(c >> 3)*HN + nn0 + (c & 7)*8);
      }
    }

    // S = Q K^T : 8 MFMAs; sacc[nt] covers keys nt*16+lc, rows quad*4+r
    f32x4 sacc[4] = {};
#pragma unroll
    for (int kk = 0; kk < 2; ++kk)
#pragma unroll
      for (int nt = 0; nt < 4; ++nt) {
        bf16x8 bk = *(const bf16x8*)(&Ks[nt*16 + lc][kk*32 + quad*8]);
        sacc[nt] = mfma16(aq[kk], bk, sacc[nt]);
      }

    // fixed-max softmax: p = exp2(S*log2e - 8*log2e); accumulate per-lane l
#pragma unroll
    for (int r = 0; r < 4; ++r) {
      float ps[4];
#pragma unroll
      for (int nt = 0; nt < 4; ++nt) {
        ps[nt] = fast_exp2(__builtin_fmaf(sacc[nt][r], LOG2E, -MB2));
        sacc[nt][r] = ps[nt];
      }
      l_i[r] += (ps[0] + ps[1]) + (ps[2] + ps[3]);
    }

    // P stash: C->A relayout, one ds_write_b64 per row r.
    // storage col c = lc*4 + nt <-> key nt*16+lc (matches Vtb 64-group perm)
#pragma unroll
    for (int r = 0; r < 4; ++r) {
      uint2 pk;
      pk.x = pack_bf16_rne(sacc[0][r], sacc[1][r]);
      pk.y = pack_bf16_rne(sacc[2][r], sacc[3][r]);
      *(uint2*)(&Ps[w][quad*4 + r][lc*4]) = pk;
    }

    // O += P V : 8 MFMAs (A from Ps, B from Vts; both in permuted key space)
#pragma unroll
    for (int kk = 0; kk < 2; ++kk) {
      bf16x8 ap = *(const bf16x8*)(&Ps[w][lc][kk*32 + quad*8]);
#pragma unroll
      for (int nt2 = 0; nt2 < 4; ++nt2) {
        bf16x8 bv = *(const bf16x8*)(&Vts[nt2*16 + lc][kk*32 + quad*8]);
        oacc[nt2] = mfma16(ap, bv, oacc[nt2]);
      }
    }

    if (ck < 15) {
      __syncthreads();   // all waves done reading Ks/Vts
#pragma unroll
      for (int i = 0; i < 2; ++i) {
        const int c = i*256 + tid;
        *(bf16x8*)(&Ks [c >> 3][(c & 7)*8]) = gk[i];
        *(bf16x8*)(&Vts[c >> 3][(c & 7)*8]) = gv[i];
      }
      __syncthreads();
    }
  }

  // epilogue: reduce l across the 16 lanes of each quad, then scale & store
  float rl[4];
#pragma unroll
  for (int r = 0; r < 4; ++r) {
    float l = l_i[r];
#pragma unroll
    for (int off = 1; off < 16; off <<= 1) l += __shfl_xor(l, off);
    rl[r] = 1.0f / l;
  }
#pragma unroll
  for (int nt2 = 0; nt2 < 4; ++nt2)
#pragma unroll
    for (int r = 0; r < 4; ++r) {
      const int row = qt*64 + w*16 + quad*4 + r;
      const int d   = nt2*16 + lc;
      AOb[((size_t)(b*HN + row))*HC + h*HD + d] = f2bf(oacc[nt2][r] * rl[r]);
    }
}

// ---------------- launch ----------------
extern "C" void kernel_launch(void* const* d_in, const int* in_sizes, int n_in,
                              void* d_out, int out_size, void* d_ws, size_t ws_size,
                              hipStream_t stream) {
  const float* x     = (const float*)d_in[0];
  const float* wqkv  = (const float*)d_in[1];
  const float* wproj = (const float*)d_in[2];
  float* out = (float*)d_out;

  char* ws = (char*)d_ws;
  size_t off = 0;
  auto alloc = [&](size_t bytes) -> void* {
    void* p = ws + off; off += (bytes + 255) & ~(size_t)255; return p;
  };
  short* xb     = (short*)alloc((size_t)ROWS*HC*2);        // 12.6 MB
  short* wqkvb  = (short*)alloc((size_t)3*HC*HC*2);        //  3.5 MB
  short* wprojb = (short*)alloc((size_t)HC*HC*2);          //  1.2 MB
  short* Qb     = (short*)alloc((size_t)BH*HN*HD*2);       // 12.6 MB
  short* Kb     = (short*)alloc((size_t)BH*HN*HD*2);       // 12.6 MB
  short* Vtb    = (short*)alloc((size_t)BH*HD*HN*2);       // 12.6 MB
  short* AOb    = (short*)alloc((size_t)ROWS*HC*2);        // 12.6 MB  (~68 MB total)

  { const int n0 = ROWS*HC/4, n1 = 3*HC*HC/4, n2 = HC*HC/4;
    const int tot = n0 + n1 + n2;
    cvt3_kernel<<<(tot + 255)/256, 256, 0, stream>>>(x, xb, n0, wqkv, wqkvb, n1,
                                                     wproj, wprojb, n2); }

  gemm_qkv<<<18*64, 256, 0, stream>>>(xb, wqkvb, Qb, Kb, Vtb);
  attn_kernel<<<BH*16, 256, 0, stream>>>(Qb, Kb, Vtb, AOb);
  gemm_bt_f32<<<6*64, 256, 0, stream>>>(AOb, wprojb, out, ROWS, HC, HC);
}

// Round 9
// 203.171 us; speedup vs baseline: 1.1294x; 1.1294x over previous
//
#include <hip/hip_runtime.h>
#include <stdint.h>
#include <stddef.h>

// Problem constants
#define HB 8
#define HN 1024
#define HC 768
#define HH 12
#define HD 64
#define ROWS (HB*HN)      // 8192
#define BH (HB*HH)        // 96

using s16x4  = __attribute__((ext_vector_type(4))) short;
using bf16x8 = __attribute__((ext_vector_type(8))) short;
using f32x4  = __attribute__((ext_vector_type(4))) float;

__device__ __forceinline__ short f2bf(float f) {
  union { float f; uint32_t u; } c; c.f = f;
  uint32_t u = c.u;
  uint32_t r = (u + 0x7fffu + ((u >> 16) & 1u)) >> 16;   // RNE
  return (short)r;
}
__device__ __forceinline__ float bf2f(short s) {
  union { uint32_t u; float f; } c; c.u = ((uint32_t)(uint16_t)s) << 16;
  return c.f;
}
// pack two f32 -> {bf16(a) | bf16(b)<<16} with RNE, via v_perm_b32
__device__ __forceinline__ uint32_t pack_bf16_rne(float a, float b) {
  union { float f; uint32_t u; } ca, cb; ca.f = a; cb.f = b;
  uint32_t ra = ca.u + 0x7fffu + ((ca.u >> 16) & 1u);
  uint32_t rb = cb.u + 0x7fffu + ((cb.u >> 16) & 1u);
  return __builtin_amdgcn_perm(rb, ra, 0x07060302);  // {rb[31:16], ra[31:16]}
}
__device__ __forceinline__ float fast_exp2(float x) {
#if __has_builtin(__builtin_amdgcn_exp2f)
  return __builtin_amdgcn_exp2f(x);
#else
  return exp2f(x);
#endif
}
__device__ __forceinline__ f32x4 mfma16(bf16x8 a, bf16x8 b, f32x4 c) {
  return __builtin_amdgcn_mfma_f32_16x16x32_bf16(a, b, c, 0, 0, 0);
}
// async global->LDS, 16B per lane. LDS dest MUST be wave-uniform base + lane*16.
__device__ __forceinline__ void gll16(const void* g, void* l) {
  __builtin_amdgcn_global_load_lds((const __attribute__((address_space(1))) void*)g,
                                   (__attribute__((address_space(3))) void*)l,
                                   16, 0, 0);
}

// ---------------- fused f32 -> bf16 convert for all 3 inputs ----------------
__global__ void cvt3_kernel(const float* __restrict__ x,  short* __restrict__ xb,  int n0,
                            const float* __restrict__ wq, short* __restrict__ wqb, int n1,
                            const float* __restrict__ wp, short* __restrict__ wpb, int n2) {
  int i = blockIdx.x * 256 + threadIdx.x;        // index in float4 units
  const float* in; short* out;
  if (i < n0)            { in = x;  out = xb;  }
  else if (i < n0 + n1)  { i -= n0; in = wq; out = wqb; }
  else if (i < n0 + n1 + n2) { i -= n0 + n1; in = wp; out = wpb; }
  else return;
  float4 v = ((const float4*)in)[i];
  s16x4 o;
  o.x = f2bf(v.x); o.y = f2bf(v.y); o.z = f2bf(v.z); o.w = f2bf(v.w);
  ((s16x4*)out)[i] = o;
}

__device__ __forceinline__ void store_c(float* p, float v) { *p = v; }
__device__ __forceinline__ void store_c(short* p, float v) { *p = f2bf(v); }

// ---------------- GEMM 1: qkv = x*Wqkv^T with fused per-head LN epilogue -----
// R6 structure exactly (plain launch bounds — R8's (256,3) attempt crashed).
__global__ __launch_bounds__(256) void gemm_qkv(const short* __restrict__ A,
                                                const short* __restrict__ Bw,
                                                short* __restrict__ Qb,
                                                short* __restrict__ Kb,
                                                short* __restrict__ vb) {
  const int K = HC;
  __shared__ short As[128*64];
  __shared__ short Bs[128*64];
  const int m0 = blockIdx.y * 128, n0 = blockIdx.x * 128;
  const int tid = threadIdx.x;
  const int lane = tid & 63, w = tid >> 6, quad = lane >> 4, lc = lane & 15;
  const int wr = w >> 1, wc = w & 1;
  f32x4 acc[4][4] = {};
  for (int kt = 0; kt < K; kt += 64) {
#pragma unroll
    for (int i = 0; i < 4; ++i) {
      const int chunk = i*256 + tid;
      const int r = chunk >> 3, cb = chunk & 7;
      const int cbs = cb ^ (r & 7);
      gll16(A  + (size_t)(m0 + r)*K + kt + cbs*8, (void*)(As + (size_t)chunk*8));
      gll16(Bw + (size_t)(n0 + r)*K + kt + cbs*8, (void*)(Bs + (size_t)chunk*8));
    }
    __syncthreads();
#pragma unroll
    for (int kk = 0; kk < 2; ++kk) {
      bf16x8 af[4], bfr[4];
      const int kb = kk*4 + quad;
#pragma unroll
      for (int mt = 0; mt < 4; ++mt)
        af[mt] = *(const bf16x8*)(As + (wr*64 + mt*16 + lc)*64 + (kb ^ (lc & 7))*8);
#pragma unroll
      for (int nt = 0; nt < 4; ++nt)
        bfr[nt] = *(const bf16x8*)(Bs + (wc*64 + nt*16 + lc)*64 + (kb ^ (lc & 7))*8);
#pragma unroll
      for (int mt = 0; mt < 4; ++mt)
#pragma unroll
        for (int nt = 0; nt < 4; ++nt)
          acc[mt][nt] = mfma16(af[mt], bfr[nt], acc[mt][nt]);
    }
    __syncthreads();
  }
  // epilogue (C/D: col=nt*16+lc, row=quad*4+r)
  const int cg = n0 + wc*64;
  const int t = cg / HC;                // 0=q, 1=k, 2=v
  const int h = (cg % HC) / HD;
  const int b = m0 >> 10;
  const int bh = b*HH + h;
  if (t < 2) {
    short* outp = (t == 0) ? Qb : Kb;
    const float sc = (t == 0) ? 0.125f : 1.0f;   // SCALE = 64^-0.5 for q
#pragma unroll
    for (int mt = 0; mt < 4; ++mt)
#pragma unroll
      for (int r = 0; r < 4; ++r) {
        float s1 = (acc[mt][0][r] + acc[mt][1][r]) + (acc[mt][2][r] + acc[mt][3][r]);
        float s2 = acc[mt][0][r]*acc[mt][0][r];
        s2 = __builtin_fmaf(acc[mt][1][r], acc[mt][1][r], s2);
        s2 = __builtin_fmaf(acc[mt][2][r], acc[mt][2][r], s2);
        s2 = __builtin_fmaf(acc[mt][3][r], acc[mt][3][r], s2);
#pragma unroll
        for (int off = 1; off < 16; off <<= 1) {
          s1 += __shfl_xor(s1, off);
          s2 += __shfl_xor(s2, off);
        }
        const float mean = s1 * (1.0f/64.0f);
        const float var  = s2 * (1.0f/64.0f) - mean*mean;
        const float inv  = rsqrtf(var + 1e-5f) * sc;
        const int n_in = (m0 & 1023) + wr*64 + mt*16 + quad*4 + r;
        short* rowp = outp + ((size_t)bh*HN + n_in)*HD;
#pragma unroll
        for (int nt = 0; nt < 4; ++nt)
          rowp[nt*16 + lc] = f2bf((acc[mt][nt][r] - mean) * inv);
      }
  } else {
#pragma unroll
    for (int mt = 0; mt < 4; ++mt)
#pragma unroll
      for (int nt = 0; nt < 4; ++nt)
#pragma unroll
        for (int r = 0; r < 4; ++r) {
          const int row = m0 + wr*64 + mt*16 + quad*4 + r;
          const int col = h*HD + nt*16 + lc;
          vb[(size_t)row*HC + col] = f2bf(acc[mt][nt][r]);
        }
  }
}

// ---------------- GEMM 2: out = AO * Wproj^T (f32 out) ----------------------
__global__ __launch_bounds__(256) void gemm_bt_f32(const short* __restrict__ A,
                                                   const short* __restrict__ Bw,
                                                   float* __restrict__ C,
                                                   int M, int N, int K) {
  __shared__ short As[128*64];
  __shared__ short Bs[128*64];
  const int m0 = blockIdx.y * 128, n0 = blockIdx.x * 128;
  const int tid = threadIdx.x;
  const int lane = tid & 63, w = tid >> 6, quad = lane >> 4, lc = lane & 15;
  const int wr = w >> 1, wc = w & 1;
  f32x4 acc[4][4] = {};
  for (int kt = 0; kt < K; kt += 64) {
#pragma unroll
    for (int i = 0; i < 4; ++i) {
      const int chunk = i*256 + tid;
      const int r = chunk >> 3, cb = chunk & 7;
      const int cbs = cb ^ (r & 7);
      gll16(A  + (size_t)(m0 + r)*K + kt + cbs*8, (void*)(As + (size_t)chunk*8));
      gll16(Bw + (size_t)(n0 + r)*K + kt + cbs*8, (void*)(Bs + (size_t)chunk*8));
    }
    __syncthreads();
#pragma unroll
    for (int kk = 0; kk < 2; ++kk) {
      bf16x8 af[4], bfr[4];
      const int kb = kk*4 + quad;
#pragma unroll
      for (int mt = 0; mt < 4; ++mt)
        af[mt] = *(const bf16x8*)(As + (wr*64 + mt*16 + lc)*64 + (kb ^ (lc & 7))*8);
#pragma unroll
      for (int nt = 0; nt < 4; ++nt)
        bfr[nt] = *(const bf16x8*)(Bs + (wc*64 + nt*16 + lc)*64 + (kb ^ (lc & 7))*8);
#pragma unroll
      for (int mt = 0; mt < 4; ++mt)
#pragma unroll
        for (int nt = 0; nt < 4; ++nt)
          acc[mt][nt] = mfma16(af[mt], bfr[nt], acc[mt][nt]);
    }
    __syncthreads();
  }
#pragma unroll
  for (int mt = 0; mt < 4; ++mt)
#pragma unroll
    for (int nt = 0; nt < 4; ++nt)
#pragma unroll
      for (int r = 0; r < 4; ++r) {
        const int row = m0 + wr*64 + mt*16 + quad*4 + r;
        const int col = n0 + wc*64 + nt*16 + lc;
        store_c(C + (size_t)row*N + col, acc[mt][nt][r]);
      }
}

// ---------------- V transpose/permute: vb [8192][768] -> Vtb [BH][64][1024] --
// Key-permuted per 64-chunk: storage col c (within 64-group) holds key
// k(c) = (c&3)*16 + (c>>2)  — matches the b64 P stash in attn.
__global__ __launch_bounds__(256) void vtrans_kernel(const short* __restrict__ vb,
                                                     short* __restrict__ Vtb) {
  const int blk = blockIdx.x;            // bh*8 + tile
  const int tile = blk & 7, bh = blk >> 3;
  const int b = bh / HH, h = bh % HH;
  const int n0 = tile * 128;
  const int tid = threadIdx.x;
  __shared__ float vt[128][65];
#pragma unroll
  for (int i = 0; i < 32; ++i) {
    const int idx = i*256 + tid; const int r = idx >> 6, dcol = idx & 63;
    vt[r][dcol] = bf2f(vb[(size_t)(b*HN + n0 + r)*HC + h*HD + dcol]);
  }
  __syncthreads();
#pragma unroll
  for (int it = 0; it < 4; ++it) {
    const int idx = it*256 + tid;
    const int dd = idx >> 4, j8 = idx & 15;   // dd in [0,64), j8 in [0,16)
    bf16x8 o;
#pragma unroll
    for (int u = 0; u < 8; ++u) {
      const int c  = j8*8 + u;                // storage col within 128-tile
      const int g  = c >> 6, cl = c & 63;     // 64-group, col within group
      const int k  = g*64 + ((cl & 3)*16 + (cl >> 2));
      o[u] = f2bf(vt[k][dd]);
    }
    *(bf16x8*)(Vtb + ((size_t)bh*HD + dd)*HN + n0 + j8*8) = o;
  }
}

// ---------------- flash attention: 128 q-rows/block, 64-key chunks ----------
// R9: each wave owns 32 q-rows (2 m-tiles) -> per chunk 32 MFMA + 32 exp
// against the SAME staging cost as R6's 16+16 -> barriers per unit work halve,
// K/V global traffic halves. Grid 768 blocks = 3/CU; LDS 36864 B.
// Regs ~125 live -> (256,3) cap 170, no spill headroom needed.
__global__ __launch_bounds__(256, 3) void attn_kernel(const short* __restrict__ Qb,
                                                      const short* __restrict__ Kb,
                                                      const short* __restrict__ Vtb,
                                                      short* __restrict__ AOb) {
  const int blk = blockIdx.x;
  const int qt = blk & 7, bh = blk >> 3;
  const int b = bh / HH, h = bh % HH;
  const int tid = threadIdx.x, w = tid >> 6, lane = tid & 63;
  const int quad = lane >> 4, lc = lane & 15;

  __shared__ short Ks [64][72];      // K chunk: row=key(natural), padded
  __shared__ short Vts[64][72];      // V chunk: row=d, cols=64 keys permuted
  __shared__ short Ps [4][32][72];   // per-wave P stash (32 q-rows), permuted keys

  // Q A-fragments: A[m=lane&15][k=quad*8+j]; wave rows qt*128 + w*32 + mt*16
  bf16x8 aq[2][2];
#pragma unroll
  for (int mt = 0; mt < 2; ++mt) {
    const int mrow = qt*128 + w*32 + mt*16 + lc;
    aq[mt][0] = *(const bf16x8*)(Qb + ((size_t)bh*HN + mrow)*HD + quad*8);
    aq[mt][1] = *(const bf16x8*)(Qb + ((size_t)bh*HN + mrow)*HD + 32 + quad*8);
  }

  const short* kbh = Kb  + (size_t)bh*HN*HD;
  const short* vbh = Vtb + (size_t)bh*HD*HN;

  f32x4 oacc[2][4] = {};
  float l_i[2][4] = {};

  // staging regs: c = i*256+tid in [0,512); row=c>>3 in [0,64), cb=c&7
  bf16x8 gk[2], gv[2];
#pragma unroll
  for (int i = 0; i < 2; ++i) {
    const int c = i*256 + tid;
    gk[i] = *(const bf16x8*)(kbh + (size_t)(c >> 3)*HD + (c & 7)*8);
    gv[i] = *(const bf16x8*)(vbh + (size_t)(c >> 3)*HN + (c & 7)*8);
  }
#pragma unroll
  for (int i = 0; i < 2; ++i) {
    const int c = i*256 + tid;
    *(bf16x8*)(&Ks [c >> 3][(c & 7)*8]) = gk[i];
    *(bf16x8*)(&Vts[c >> 3][(c & 7)*8]) = gv[i];
  }
  __syncthreads();

  const float LOG2E = 1.44269504f;
  const float MB2   = 8.0f * 1.44269504f;   // fixed max * log2(e)

  for (int ck = 0; ck < 16; ++ck) {
    // prefetch chunk ck+1 into registers (overlaps with compute below)
    if (ck < 15) {
      const int nn0 = (ck + 1)*64;
#pragma unroll
      for (int i = 0; i < 2; ++i) {
        const int c = i*256 + tid;
        gk[i] = *(const bf16x8*)(kbh + (size_t)(nn0 + (c >> 3))*HD + (c & 7)*8);
        gv[i] = *(const bf16x8*)(vbh + (size_t)(c >> 3)*HN + nn0 + (c & 7)*8);
      }
    }

    // S = Q K^T : 16 MFMAs (2 m-tiles x 2 kk x 4 nt)
    f32x4 sacc[2][4] = {};
#pragma unroll
    for (int kk = 0; kk < 2; ++kk)
#pragma unroll
      for (int nt = 0; nt < 4; ++nt) {
        bf16x8 bk = *(const bf16x8*)(&Ks[nt*16 + lc][kk*32 + quad*8]);
#pragma unroll
        for (int mt = 0; mt < 2; ++mt)
          sacc[mt][nt] = mfma16(aq[mt][kk], bk, sacc[mt][nt]);
      }

    // fixed-max softmax + P stash (C->A relayout, ds_write_b64 per row)
#pragma unroll
    for (int mt = 0; mt < 2; ++mt)
#pragma unroll
      for (int r = 0; r < 4; ++r) {
        float ps[4];
#pragma unroll
        for (int nt = 0; nt < 4; ++nt) {
          ps[nt] = fast_exp2(__builtin_fmaf(sacc[mt][nt][r], LOG2E, -MB2));
          sacc[mt][nt][r] = ps[nt];
        }
        l_i[mt][r] += (ps[0] + ps[1]) + (ps[2] + ps[3]);
        uint2 pk;
        pk.x = pack_bf16_rne(ps[0], ps[1]);
        pk.y = pack_bf16_rne(ps[2], ps[3]);
        *(uint2*)(&Ps[w][mt*16 + quad*4 + r][lc*4]) = pk;
      }

    // O += P V : 16 MFMAs (A from Ps, B from Vts; both in permuted key space)
#pragma unroll
    for (int kk = 0; kk < 2; ++kk) {
      bf16x8 ap[2];
#pragma unroll
      for (int mt = 0; mt < 2; ++mt)
        ap[mt] = *(const bf16x8*)(&Ps[w][mt*16 + lc][kk*32 + quad*8]);
#pragma unroll
      for (int nt2 = 0; nt2 < 4; ++nt2) {
        bf16x8 bv = *(const bf16x8*)(&Vts[nt2*16 + lc][kk*32 + quad*8]);
#pragma unroll
        for (int mt = 0; mt < 2; ++mt)
          oacc[mt][nt2] = mfma16(ap[mt], bv, oacc[mt][nt2]);
      }
    }

    if (ck < 15) {
      __syncthreads();   // all waves done reading Ks/Vts
#pragma unroll
      for (int i = 0; i < 2; ++i) {
        const int c = i*256 + tid;
        *(bf16x8*)(&Ks [c >> 3][(c & 7)*8]) = gk[i];
        *(bf16x8*)(&Vts[c >> 3][(c & 7)*8]) = gv[i];
      }
      __syncthreads();
    }
  }

  // epilogue: reduce l across the 16 lanes of each quad, then scale & store
#pragma unroll
  for (int mt = 0; mt < 2; ++mt)
#pragma unroll
    for (int r = 0; r < 4; ++r) {
      float l = l_i[mt][r];
#pragma unroll
      for (int off = 1; off < 16; off <<= 1) l += __shfl_xor(l, off);
      const float rl = 1.0f / l;
      const int row = qt*128 + w*32 + mt*16 + quad*4 + r;
#pragma unroll
      for (int nt2 = 0; nt2 < 4; ++nt2) {
        const int d = nt2*16 + lc;
        AOb[((size_t)(b*HN + row))*HC + h*HD + d] = f2bf(oacc[mt][nt2][r] * rl);
      }
    }
}

// ---------------- launch ----------------
extern "C" void kernel_launch(void* const* d_in, const int* in_sizes, int n_in,
                              void* d_out, int out_size, void* d_ws, size_t ws_size,
                              hipStream_t stream) {
  const float* x     = (const float*)d_in[0];
  const float* wqkv  = (const float*)d_in[1];
  const float* wproj = (const float*)d_in[2];
  float* out = (float*)d_out;

  char* ws = (char*)d_ws;
  size_t off = 0;
  auto alloc = [&](size_t bytes) -> void* {
    void* p = ws + off; off += (bytes + 255) & ~(size_t)255; return p;
  };
  short* xb     = (short*)alloc((size_t)ROWS*HC*2);        // 12.6 MB
  short* wqkvb  = (short*)alloc((size_t)3*HC*HC*2);        //  3.5 MB
  short* wprojb = (short*)alloc((size_t)HC*HC*2);          //  1.2 MB
  short* vb     = (short*)alloc((size_t)ROWS*HC*2);        // 12.6 MB
  short* Qb     = (short*)alloc((size_t)BH*HN*HD*2);       // 12.6 MB
  short* Kb     = (short*)alloc((size_t)BH*HN*HD*2);       // 12.6 MB
  short* Vtb    = (short*)alloc((size_t)BH*HD*HN*2);       // 12.6 MB
  short* AOb    = (short*)alloc((size_t)ROWS*HC*2);        // 12.6 MB  (~80 MB total)

  { const int n0 = ROWS*HC/4, n1 = 3*HC*HC/4, n2 = HC*HC/4;
    const int tot = n0 + n1 + n2;
    cvt3_kernel<<<(tot + 255)/256, 256, 0, stream>>>(x, xb, n0, wqkv, wqkvb, n1,
                                                     wproj, wprojb, n2); }

  gemm_qkv<<<dim3(3*HC/128, ROWS/128), 256, 0, stream>>>(xb, wqkvb, Qb, Kb, vb);
  vtrans_kernel<<<BH*8, 256, 0, stream>>>(vb, Vtb);
  attn_kernel<<<BH*8, 256, 0, stream>>>(Qb, Kb, Vtb, AOb);
  gemm_bt_f32<<<dim3(HC/128, ROWS/128), 256, 0, stream>>>(AOb, wprojb, out,
                                                          ROWS, HC, HC);
}